// Round 12
// baseline (690.664 us; speedup 1.0000x reference)
//
#include <hip/hip_runtime.h>

// ---------------------------------------------------------------------------
// MultiModalRelationGraph — R12
// - GEMM: R7 BK=64 dbuf + NEW B-frag loads hoisted BEFORE the prefetch DMAs.
//   vmcnt retires in order: previously the MFMA's wait for B (last issued)
//   implied vmcnt(0), draining the HBM prefetch every iteration. Hoisting B
//   lets the compiler wait at vmcnt(8) and keeps the prefetch in flight.
// - L0 fused: h0 = in @ Wc + bc, where Wc = Wr@W0, bc = br@W0 precomputed
//   on-device (cvt Wr->bf16, Wc via the same gemm kernel + pack; exact math).
//   Replaces proj + L0-GEMM + x0 round-trip with one dispatch.
// - Agg (R11 merged 6-dst blocks): !MEAN path now barrier-free — wave w ==
//   head w computes its dots via wredx and its softmax per-lane (redundant
//   within the wave = free SIMD lanes); no LDS. MEAN path = R11 verbatim.
// - Ledger: agg strip-mining loses TLP (R8/R9); per-node atomics flood (R10);
//   pure-global GEMM operands are L2-BW-bound (R5); big-tile AGPRs kill
//   occupancy (R3).
// Node layout: region i in [i*8192,(i+1)*8192), node = i*8192 + b*512 + t.
// Audio: 32768 + b*1024 + ta.
// ---------------------------------------------------------------------------

typedef unsigned short u16;
typedef unsigned int u32;
typedef __bf16 bf16x8 __attribute__((ext_vector_type(8)));
typedef float f32x4 __attribute__((ext_vector_type(4)));

#define ASYNC16(gp, lp)                                                        \
  __builtin_amdgcn_global_load_lds(                                            \
      (const __attribute__((address_space(1))) void*)(gp),                     \
      (__attribute__((address_space(3))) void*)(lp), 16, 0, 0)

__device__ __forceinline__ u16 f2bf(float f) {
  union { float f; u32 u; } v; v.f = f;
  u32 u = v.u + 0x7FFFu + ((v.u >> 16) & 1u);  // RNE
  return (u16)(u >> 16);
}
__device__ __forceinline__ float bf2f(u16 x) {
  union { u32 u; float f; } v; v.u = ((u32)x) << 16;
  return v.f;
}
__device__ __forceinline__ float4 load_bf4(const u16* p) {
  ushort4 s = *(const ushort4*)p;
  float4 r; r.x = bf2f(s.x); r.y = bf2f(s.y); r.z = bf2f(s.z); r.w = bf2f(s.w);
  return r;
}
__device__ __forceinline__ float lrelu(float v) { return v > 0.f ? v : 0.2f * v; }
__device__ __forceinline__ float dot4(float4 a, float4 b) {
  return a.x * b.x + a.y * b.y + a.z * b.z + a.w * b.w;
}
__device__ __forceinline__ float wred(float v) {  // lane 0 valid
#pragma unroll
  for (int off = 32; off; off >>= 1) v += __shfl_down(v, off);
  return v;
}
__device__ __forceinline__ float wredx(float v) {  // all lanes valid
#pragma unroll
  for (int off = 32; off; off >>= 1) v += __shfl_xor(v, off);
  return v;
}

// ---------------- weight pack: W [K][N] fp32 -> MFMA B-fragment order -------
struct PK { const float* W[3]; u16* P[3]; int KB[3]; int NN[3]; int st[4]; };
__global__ __launch_bounds__(256) void pack_kernel(PK p) {
  const int f = blockIdx.x * 4 + (threadIdx.x >> 6);
  const int lane = threadIdx.x & 63;
  int e = 0;
  while (f >= p.st[e + 1]) ++e;
  const int local = f - p.st[e];
  const int KB = p.KB[e], N = p.NN[e];
  const int nt = local / KB, kb = local % KB;
  const float* W = p.W[e] + (size_t)(kb * 32 + (lane >> 4) * 8) * N + nt * 16 + (lane & 15);
  u16* dst = p.P[e] + ((size_t)local * 64 + lane) * 8;
  u16 o[8];
#pragma unroll
  for (int j = 0; j < 8; ++j) o[j] = f2bf(W[(size_t)j * N]);
  *(uint4*)dst = *(uint4*)o;
}

// ---------------- input-proj weights fp32 -> bf16 stacked [2560+pad][256] ---
struct CW { const float* w[5]; };
__global__ __launch_bounds__(256) void cvtw_kernel(CW a, u16* __restrict__ dst) {
  const int i = blockIdx.x * 256 + threadIdx.x;  // float4 units, 163840 total
  const float* src = a.w[i >> 15];
  float4 v = ((const float4*)src)[i & 32767];
  ushort4 o;
  o.x = f2bf(v.x); o.y = f2bf(v.y); o.z = f2bf(v.z); o.w = f2bf(v.w);
  ((ushort4*)dst)[i] = o;
}

// ---------------- bc[r] = br @ W0  ([256] @ [256,1024]) ---------------------
struct BC { const float* br[5]; };
__global__ __launch_bounds__(256) void bc_kernel(BC a, const float* __restrict__ W0,
                                                 float* __restrict__ bc) {
  const int r = blockIdx.x >> 2;
  const int n = (blockIdx.x & 3) * 256 + threadIdx.x;
  const float* b = a.br[r];
  float acc = 0.f;
  for (int k = 0; k < 256; ++k) acc += b[k] * W0[(size_t)k * 1024 + n];
  bc[r * 1024 + n] = acc;
}

// ---------------- pack Wc row-major bf16 [5*512][1024] -> fragment order ----
__global__ __launch_bounds__(256) void packwc_kernel(const u16* __restrict__ Wrm,
                                                     u16* __restrict__ P) {
  const int f = blockIdx.x * 4 + (threadIdx.x >> 6);  // 0..5119
  const int lane = threadIdx.x & 63;
  const int region = f >> 10, local = f & 1023;
  const int nt = local >> 4, kb = local & 15;  // KB=16
  const u16* W = Wrm + (size_t)(region * 512 + kb * 32 + (lane >> 4) * 8) * 1024 +
                 nt * 16 + (lane & 15);
  u16 o[8];
#pragma unroll
  for (int j = 0; j < 8; ++j) o[j] = W[(size_t)j * 1024];
  *(uint4*)(P + ((size_t)f * 64 + lane) * 8) = *(uint4*)o;
}

// ---------------- layer GEMM: C[M,N]=A[M,K]@W^T; BK=64 dbuf LDS A -----------
// B-frag loads hoisted BEFORE prefetch DMAs (vmcnt in-order retirement).
// gridDim.x must be 8; row tiles must be a multiple of 8.
__global__ __launch_bounds__(256) void gemm_kernel(
    const u16* __restrict__ A, const u16* __restrict__ Bp, u16* __restrict__ C,
    int K, int ldc) {
  __shared__ __align__(16) u16 As[2][2][128 * 32];
  const int KB = K >> 5;
  const int KB2 = K >> 6;
  const int w = blockIdx.y * 8 + blockIdx.x;
  const int xcd = w & 7, m = w >> 3;
  const int blockCol = (m & 7) * 128;
  const int blockRow = ((m >> 3) * 8 + xcd) * 128;
  const int tid = threadIdx.x;
  const int wave = tid >> 6, lane = tid & 63;
  const int wr = (wave >> 1) * 64, wc = (wave & 1) * 64;
  const int lr = lane & 15, lq = lane >> 4;
  const int sRow = wave * 16 + (lane >> 2);
  const int sGc = (lane & 3) ^ ((sRow >> 1) & 3);
  const size_t aOff0 = (size_t)(blockRow + sRow) * K + sGc * 8;
  const size_t aOff1 = aOff0 + (size_t)64 * K;
  const int ldsOff0 = wave * 512;
  const int ldsOff1 = 2048 + wave * 512;

  const u16* Bn[4];
#pragma unroll
  for (int ni = 0; ni < 4; ++ni)
    Bn[ni] = Bp + ((size_t)(((blockCol + wc) >> 4) + ni) * KB) * 512 + lane * 8;

  f32x4 acc[4][4] = {};

#pragma unroll
  for (int h = 0; h < 2; ++h) {
    ASYNC16(A + aOff0 + h * 32, As[0][h] + ldsOff0);
    ASYNC16(A + aOff1 + h * 32, As[0][h] + ldsOff1);
  }
  __syncthreads();

  for (int kb2 = 0; kb2 < KB2; ++kb2) {
    const int cb = kb2 & 1;
    // 1) B fragments for BOTH halves first: their vmcnt wait then excludes
    //    the prefetch DMAs issued below (in-order retirement).
    bf16x8 bfr[2][4];
#pragma unroll
    for (int h = 0; h < 2; ++h)
#pragma unroll
      for (int ni = 0; ni < 4; ++ni)
        bfr[h][ni] = *(const bf16x8*)(Bn[ni] + (size_t)(kb2 * 2 + h) * 512);
    // 2) prefetch next 64-wide A block
    if (kb2 + 1 < KB2) {
      const size_t k1 = (size_t)(kb2 + 1) * 64;
#pragma unroll
      for (int h = 0; h < 2; ++h) {
        ASYNC16(A + aOff0 + k1 + h * 32, As[cb ^ 1][h] + ldsOff0);
        ASYNC16(A + aOff1 + k1 + h * 32, As[cb ^ 1][h] + ldsOff1);
      }
    }
    // 3) compute
#pragma unroll
    for (int h = 0; h < 2; ++h) {
      const u16* cur = As[cb][h];
      bf16x8 af[4];
#pragma unroll
      for (int mi = 0; mi < 4; ++mi) {
        const int R = wr + mi * 16 + lr;
        const int cp = lq ^ ((R >> 1) & 3);
        af[mi] = *(const bf16x8*)(cur + R * 32 + cp * 8);
      }
#pragma unroll
      for (int mi = 0; mi < 4; ++mi)
#pragma unroll
        for (int ni = 0; ni < 4; ++ni)
          acc[mi][ni] = __builtin_amdgcn_mfma_f32_16x16x32_bf16(af[mi], bfr[h][ni],
                                                                acc[mi][ni], 0, 0, 0);
    }
    __syncthreads();
  }
#pragma unroll
  for (int mi = 0; mi < 4; ++mi)
#pragma unroll
    for (int ni = 0; ni < 4; ++ni) {
      const int col = blockCol + wc + ni * 16 + lr;
#pragma unroll
      for (int r = 0; r < 4; ++r) {
        const int row = blockRow + wr + mi * 16 + lq * 4 + r;
        C[(size_t)row * ldc + col] = f2bf(acc[mi][ni][r]);
      }
    }
}

// ---------------- fused L0: h0[N,1024] = in_fp32 @ Wc + bc ------------------
struct P0Args { const float* x[5]; };
__global__ __launch_bounds__(256) void projL0_kernel(P0Args pa,
                                                     const u16* __restrict__ Bp0,
                                                     const float* __restrict__ bc,
                                                     u16* __restrict__ C) {
  __shared__ __align__(16) u16 As[128 * 32];
  const int w = blockIdx.y * 8 + blockIdx.x;
  const int xcd = w & 7, m = w >> 3;
  const int blockCol = (m & 7) * 128;
  const int blockRow = ((m >> 3) * 8 + xcd) * 128;
  const int reg = blockRow >= 32768 ? 4 : (blockRow >> 13);
  const int regBase = reg == 4 ? 32768 : reg * 8192;
  const float* Af = pa.x[reg] + (size_t)(blockRow - regBase) * 512;
  const u16* Bp = Bp0 + (size_t)reg * 524288;  // 1024 frags x 512 el
  const int tid = threadIdx.x;
  const int wave = tid >> 6, lane = tid & 63;
  const int wr = (wave >> 1) * 64, wc = (wave & 1) * 64;
  const int lr = lane & 15, lq = lane >> 4;
  const int rr = tid >> 2;
  const int cphys = tid & 3;
  const int sGc = cphys ^ ((tid >> 3) & 3);

  const u16* Bn[4];
#pragma unroll
  for (int ni = 0; ni < 4; ++ni)
    Bn[ni] = Bp + ((size_t)(((blockCol + wc) >> 4) + ni) * 16) * 512 + lane * 8;

  f32x4 acc[4][4] = {};

  for (int k0 = 0; k0 < 512; k0 += 32) {
    __syncthreads();
    bf16x8 bfr[4];
#pragma unroll
    for (int ni = 0; ni < 4; ++ni)
      bfr[ni] = *(const bf16x8*)(Bn[ni] + (size_t)k0 * 16);
#pragma unroll
    for (int i = 0; i < 2; ++i) {
      const int row = i * 64 + rr;
      const float* ap = Af + (size_t)row * 512 + k0 + sGc * 8;
      float4 f0 = *(const float4*)(ap);
      float4 f1 = *(const float4*)(ap + 4);
      uint4 pk;
      pk.x = (u32)f2bf(f0.x) | ((u32)f2bf(f0.y) << 16);
      pk.y = (u32)f2bf(f0.z) | ((u32)f2bf(f0.w) << 16);
      pk.z = (u32)f2bf(f1.x) | ((u32)f2bf(f1.y) << 16);
      pk.w = (u32)f2bf(f1.z) | ((u32)f2bf(f1.w) << 16);
      *(uint4*)(&As[row * 32 + cphys * 8]) = pk;
    }
    __syncthreads();
    bf16x8 af[4];
#pragma unroll
    for (int mi = 0; mi < 4; ++mi) {
      const int R = wr + mi * 16 + lr;
      const int cp = lq ^ ((R >> 1) & 3);
      af[mi] = *(const bf16x8*)(&As[R * 32 + cp * 8]);
    }
#pragma unroll
    for (int mi = 0; mi < 4; ++mi)
#pragma unroll
      for (int ni = 0; ni < 4; ++ni)
        acc[mi][ni] = __builtin_amdgcn_mfma_f32_16x16x32_bf16(af[mi], bfr[ni],
                                                              acc[mi][ni], 0, 0, 0);
  }
  const float* bias = bc + reg * 1024;
#pragma unroll
  for (int mi = 0; mi < 4; ++mi)
#pragma unroll
    for (int ni = 0; ni < 4; ++ni) {
      const int col = blockCol + wc + ni * 16 + lr;
      const float bv = bias[col];
#pragma unroll
      for (int r = 0; r < 4; ++r) {
        const int row = blockRow + wr + mi * 16 + lq * 4 + r;
        C[(size_t)row * 1024 + col] = f2bf(acc[mi][ni][r] + bv);
      }
    }
}

// ---------------- merged aggregation: block (b,t) -> 6 dst nodes ------------
// !MEAN: barrier-free — wave w == head w computes its own dots (wredx) and
// softmax per-lane (redundant across the wave's lanes = free SIMD).
// MEAN: R11 path verbatim (wred lane0 -> LDS -> 20-thr softmax -> head-mean).
template <bool MEAN>
__global__ __launch_bounds__(256) void agg_kernel(
    const u16* __restrict__ h, const float* __restrict__ a_s,
    const float* __restrict__ a_d, const float* __restrict__ bias,
    void* __restrict__ out) {
  extern __shared__ float red[];  // MEAN only
  const int tid = threadIdx.x;
  const int head = tid >> 6, lane = tid & 63;
  const int c4 = tid * 4;
  const float4 sa = *(const float4*)(a_s + c4);
  const float4 da = *(const float4*)(a_d + c4);

  const int bt = blockIdx.x;
  const int b = bt >> 9, t = bt & 511;
  const bool hasPrev = t > 0;
  const int nodeE = 32768 + b * 1024 + 2 * t;
  const int nodeO = nodeE + 1;

  float4 hv[4], hp[4];
#pragma unroll
  for (int r = 0; r < 4; ++r)
    hv[r] = load_bf4(h + (size_t)(r * 8192 + bt) * 1024 + c4);
  float4 hae = load_bf4(h + (size_t)nodeE * 1024 + c4);
  float4 hao = load_bf4(h + (size_t)nodeO * 1024 + c4);
  if (hasPrev) {
#pragma unroll
    for (int r = 0; r < 4; ++r)
      hp[r] = load_bf4(h + (size_t)(r * 8192 + bt - 1) * 1024 + c4);
  }

  if constexpr (!MEAN) {
    // barrier-free per-wave path
    float ss[4], dd[4], sp[4];
#pragma unroll
    for (int r = 0; r < 4; ++r) {
      ss[r] = wredx(dot4(hv[r], sa));
      dd[r] = wredx(dot4(hv[r], da));
    }
    if (hasPrev) {
#pragma unroll
      for (int r = 0; r < 4; ++r) sp[r] = wredx(dot4(hp[r], sa));
    }
    const float se = wredx(dot4(hae, sa));
    const float de = wredx(dot4(hae, da));

    const float4 bv = *(const float4*)(bias + c4);
    u16* ob = (u16*)out;
#pragma unroll
    for (int j = 0; j < 4; ++j) {
      const float ad = dd[j];
      float e0 = lrelu(ss[0] + ad), e1 = lrelu(ss[1] + ad);
      float e2 = lrelu(ss[2] + ad), e3 = lrelu(ss[3] + ad);
      float mx = fmaxf(fmaxf(e0, e1), fmaxf(e2, e3));
      float e4 = 0.f;
      if (hasPrev) { e4 = lrelu(sp[j] + ad); mx = fmaxf(mx, e4); }
      const float x0 = __expf(e0 - mx), x1 = __expf(e1 - mx);
      const float x2 = __expf(e2 - mx), x3 = __expf(e3 - mx);
      const float x4 = hasPrev ? __expf(e4 - mx) : 0.f;
      const float inv = 1.f / (x0 + x1 + x2 + x3 + x4 + 1e-16f);
      const float a0 = x0 * inv, a1 = x1 * inv, a2 = x2 * inv, a3 = x3 * inv;
      const float a4 = x4 * inv;
      float4 acc;
      acc.x = a0 * hv[0].x + a1 * hv[1].x + a2 * hv[2].x + a3 * hv[3].x;
      acc.y = a0 * hv[0].y + a1 * hv[1].y + a2 * hv[2].y + a3 * hv[3].y;
      acc.z = a0 * hv[0].z + a1 * hv[1].z + a2 * hv[2].z + a3 * hv[3].z;
      acc.w = a0 * hv[0].w + a1 * hv[1].w + a2 * hv[2].w + a3 * hv[3].w;
      if (hasPrev) {
        acc.x += a4 * hp[j].x; acc.y += a4 * hp[j].y;
        acc.z += a4 * hp[j].z; acc.w += a4 * hp[j].w;
      }
      ushort4 o;
      o.x = f2bf(acc.x + bv.x); o.y = f2bf(acc.y + bv.y);
      o.z = f2bf(acc.z + bv.z); o.w = f2bf(acc.w + bv.w);
      *(ushort4*)(ob + (size_t)(j * 8192 + bt) * 1024 + c4) = o;
    }
    {
      const float e0 = lrelu(se + de);
      const float e1 = lrelu(ss[1] + de);
      const float e2 = lrelu(ss[2] + de);
      const float mx = fmaxf(e0, fmaxf(e1, e2));
      const float x0 = __expf(e0 - mx), x1 = __expf(e1 - mx), x2 = __expf(e2 - mx);
      const float inv = 1.f / (x0 + x1 + x2 + 1e-16f);
      const float a0 = x0 * inv, a1 = x1 * inv, a2 = x2 * inv;
      float4 acc;
      acc.x = a0 * hae.x + a1 * hv[1].x + a2 * hv[2].x;
      acc.y = a0 * hae.y + a1 * hv[1].y + a2 * hv[2].y;
      acc.z = a0 * hae.z + a1 * hv[1].z + a2 * hv[2].z;
      acc.w = a0 * hae.w + a1 * hv[1].w + a2 * hv[2].w;
      ushort4 oe, oo;
      oe.x = f2bf(acc.x + bv.x); oe.y = f2bf(acc.y + bv.y);
      oe.z = f2bf(acc.z + bv.z); oe.w = f2bf(acc.w + bv.w);
      oo.x = f2bf(hao.x + bv.x); oo.y = f2bf(hao.y + bv.y);
      oo.z = f2bf(hao.z + bv.z); oo.w = f2bf(hao.w + bv.w);
      *(ushort4*)(ob + (size_t)nodeE * 1024 + c4) = oe;
      *(ushort4*)(ob + (size_t)nodeO * 1024 + c4) = oo;
    }
  } else {
    // R11 MEAN path (LDS alphas + head-mean)
    __shared__ float asL[4][4], adL[4][4], apL[4][4], aeS[4], aeD[4];
    __shared__ float alpha[4][4][5], alphaA[4][3];
#pragma unroll
    for (int r = 0; r < 4; ++r) {
      float ss = wred(dot4(hv[r], sa));
      float dd = wred(dot4(hv[r], da));
      float sp = hasPrev ? wred(dot4(hp[r], sa)) : 0.f;
      if (lane == 0) { asL[r][head] = ss; adL[r][head] = dd; apL[r][head] = sp; }
    }
    {
      float sev = wred(dot4(hae, sa));
      float dev = wred(dot4(hae, da));
      if (lane == 0) { aeS[head] = sev; aeD[head] = dev; }
    }
    __syncthreads();
    if (tid < 16) {
      const int j = tid >> 2, hh = tid & 3;
      const float ad = adL[j][hh];
      float e[5];
#pragma unroll
      for (int r = 0; r < 4; ++r) e[r] = lrelu(asL[r][hh] + ad);
      int cnt = 4;
      if (hasPrev) { e[4] = lrelu(apL[j][hh] + ad); cnt = 5; }
      float mx = e[0];
      for (int k = 1; k < cnt; ++k) mx = fmaxf(mx, e[k]);
      float s = 0.f, ex[5];
      for (int k = 0; k < cnt; ++k) { ex[k] = __expf(e[k] - mx); s += ex[k]; }
      const float inv = 1.f / (s + 1e-16f);
#pragma unroll
      for (int k = 0; k < 5; ++k) alpha[j][hh][k] = (k < cnt) ? ex[k] * inv : 0.f;
    } else if (tid < 20) {
      const int hh = tid - 16;
      const float ad = aeD[hh];
      const float e0 = lrelu(aeS[hh] + ad);
      const float e1 = lrelu(asL[1][hh] + ad);
      const float e2 = lrelu(asL[2][hh] + ad);
      const float mx = fmaxf(e0, fmaxf(e1, e2));
      const float x0 = __expf(e0 - mx), x1 = __expf(e1 - mx), x2 = __expf(e2 - mx);
      const float inv = 1.f / (x0 + x1 + x2 + 1e-16f);
      alphaA[hh][0] = x0 * inv; alphaA[hh][1] = x1 * inv; alphaA[hh][2] = x2 * inv;
    }
    __syncthreads();

    float4 av[6];
#pragma unroll
    for (int j = 0; j < 4; ++j) {
      const float* al = &alpha[j][head][0];
      float4 acc;
      acc.x = al[0] * hv[0].x + al[1] * hv[1].x + al[2] * hv[2].x + al[3] * hv[3].x;
      acc.y = al[0] * hv[0].y + al[1] * hv[1].y + al[2] * hv[2].y + al[3] * hv[3].y;
      acc.z = al[0] * hv[0].z + al[1] * hv[1].z + al[2] * hv[2].z + al[3] * hv[3].z;
      acc.w = al[0] * hv[0].w + al[1] * hv[1].w + al[2] * hv[2].w + al[3] * hv[3].w;
      if (hasPrev) {
        const float a4 = al[4];
        acc.x += a4 * hp[j].x; acc.y += a4 * hp[j].y;
        acc.z += a4 * hp[j].z; acc.w += a4 * hp[j].w;
      }
      av[j] = acc;
    }
    {
      const float a0 = alphaA[head][0], a1 = alphaA[head][1], a2 = alphaA[head][2];
      float4 acc;
      acc.x = a0 * hae.x + a1 * hv[1].x + a2 * hv[2].x;
      acc.y = a0 * hae.y + a1 * hv[1].y + a2 * hv[2].y;
      acc.z = a0 * hae.z + a1 * hv[1].z + a2 * hv[2].z;
      acc.w = a0 * hae.w + a1 * hv[1].w + a2 * hv[2].w;
      av[4] = acc;
      av[5] = hao;
    }
#pragma unroll
    for (int k = 0; k < 6; ++k) *(float4*)(&red[k * 1024 + c4]) = av[k];
    __syncthreads();
    const float bb = bias[tid];
    float* of = (float*)out;
    size_t rows[6];
#pragma unroll
    for (int j = 0; j < 4; ++j) rows[j] = (size_t)(j * 8192 + bt);
    rows[4] = (size_t)nodeE; rows[5] = (size_t)nodeO;
#pragma unroll
    for (int k = 0; k < 6; ++k) {
      const float v = 0.25f * (red[k * 1024 + tid] + red[k * 1024 + tid + 256] +
                               red[k * 1024 + tid + 512] + red[k * 1024 + tid + 768]) + bb;
      of[rows[k] * 256 + tid] = v;
    }
  }
}

// ---------------- barrier-free LayerNorm(256) + partial pooling -------------
__global__ __launch_bounds__(256) void ln_pool_kernel(
    const float* __restrict__ xf, const float* __restrict__ g,
    const float* __restrict__ bb, float* __restrict__ part) {
  const int tid = threadIdx.x;
  const int wave = tid >> 6, lane = tid & 63;
  const int node0 = blockIdx.x * 64 + wave * 16;
  const float4 g4 = *(const float4*)(g + lane * 4);
  const float4 b4 = *(const float4*)(bb + lane * 4);
  float4 acc = {0.f, 0.f, 0.f, 0.f};
  for (int i = 0; i < 16; ++i) {
    const float4 v = *(const float4*)(xf + (size_t)(node0 + i) * 256 + lane * 4);
    const float s = wredx(v.x + v.y + v.z + v.w);
    const float q = wredx(v.x * v.x + v.y * v.y + v.z * v.z + v.w * v.w);
    const float mean = s * (1.f / 256.f);
    const float var = q * (1.f / 256.f) - mean * mean;
    const float rstd = rsqrtf(var + 1e-5f);
    acc.x += (v.x - mean) * rstd * g4.x + b4.x;
    acc.y += (v.y - mean) * rstd * g4.y + b4.y;
    acc.z += (v.z - mean) * rstd * g4.z + b4.z;
    acc.w += (v.w - mean) * rstd * g4.w + b4.w;
  }
  *(float4*)(part + (size_t)(blockIdx.x * 4 + wave) * 256 + lane * 4) = acc;
}

__global__ __launch_bounds__(256) void pool2_kernel(const float* __restrict__ part,
                                                    float* __restrict__ out) {
  const int chunk = blockIdx.x;
  const int c = threadIdx.x;
  float s = 0.f;
  for (int i = 0; i < 192; ++i) s += part[(size_t)(chunk * 192 + i) * 256 + c];
  out[chunk * 256 + c] = s * (1.f / 3072.f);
}

// ---------------------------------------------------------------------------
extern "C" void kernel_launch(void* const* d_in, const int* in_sizes, int n_in,
                              void* d_out, int out_size, void* d_ws, size_t ws_size,
                              hipStream_t stream) {
  const float* x_reg[4] = {(const float*)d_in[0], (const float*)d_in[1],
                           (const float*)d_in[2], (const float*)d_in[3]};
  const float* audio = (const float*)d_in[4];
  const float* w_reg[4] = {(const float*)d_in[5], (const float*)d_in[7],
                           (const float*)d_in[9], (const float*)d_in[11]};
  const float* b_reg[4] = {(const float*)d_in[6], (const float*)d_in[8],
                           (const float*)d_in[10], (const float*)d_in[12]};
  const float* w_aud = (const float*)d_in[13];
  const float* b_aud = (const float*)d_in[14];
  const float* Wl[3] = {(const float*)d_in[15], (const float*)d_in[19],
                        (const float*)d_in[23]};
  const float* as_in[3] = {(const float*)d_in[16], (const float*)d_in[20],
                           (const float*)d_in[24]};
  const float* ad_in[3] = {(const float*)d_in[17], (const float*)d_in[21],
                           (const float*)d_in[25]};
  const float* bias_l[3] = {(const float*)d_in[18], (const float*)d_in[22],
                            (const float*)d_in[26]};
  const float* ln_g = (const float*)d_in[27];
  const float* ln_b = (const float*)d_in[28];

  // workspace layout (<200 MiB, prep buffers alias the big dead regions)
  char* ws = (char*)d_ws;
  u16* h_bf = (u16*)ws;                       // [N,1024] bf16 (96 MiB)
  u16* wr_bf = (u16*)ws;                      // [3072][256] bf16 (1.5 MiB, alias)
  u16* wc_rm = (u16*)(ws + 2097152);          // [3072][1024] bf16 (6 MiB, alias)
  float* part = (float*)ws;                   // ln partials (h dead by then)
  u16* xb = (u16*)(ws + 100663296);           // [N,1024] bf16 x buffer
  u16* wcp = xb;                              // packed Wc (5 MiB, alias; dead after projL0)
  float* xf = (float*)xb;                     // layer-2 output [N,256] fp32
  u16* wt0 = (u16*)(ws + 201326592);          // 512 frags  (512 KiB)
  u16* wt1 = wt0 + 262144;                    // 2048 frags (2 MiB)
  u16* wt2 = wt1 + 1048576;                   // 2048 frags (2 MiB)
  float* bc = (float*)(ws + 201326592 + 4718592);  // [5][1024] fp32

  // 1) pack layer weights W0/W1/W2 into MFMA fragment order
  PK pk;
  pk.W[0] = Wl[0]; pk.P[0] = wt0; pk.KB[0] = 8;  pk.NN[0] = 1024;
  pk.W[1] = Wl[1]; pk.P[1] = wt1; pk.KB[1] = 32; pk.NN[1] = 1024;
  pk.W[2] = Wl[2]; pk.P[2] = wt2; pk.KB[2] = 32; pk.NN[2] = 1024;
  pk.st[0] = 0; pk.st[1] = 512; pk.st[2] = 2560; pk.st[3] = 4608;
  pack_kernel<<<1152, 256, 0, stream>>>(pk);

  // 2) combined L0 weights: Wc[r] = Wr @ W0 (bf16), bc[r] = br @ W0 (fp32)
  CW cw;
  for (int r = 0; r < 4; ++r) cw.w[r] = w_reg[r];
  cw.w[4] = w_aud;
  cvtw_kernel<<<640, 256, 0, stream>>>(cw, wr_bf);
  gemm_kernel<<<dim3(8, 24), 256, 0, stream>>>(wr_bf, wt0, wc_rm, 256, 1024);
  BC bca;
  for (int r = 0; r < 4; ++r) bca.br[r] = b_reg[r];
  bca.br[4] = b_aud;
  bc_kernel<<<20, 256, 0, stream>>>(bca, Wl[0], bc);
  packwc_kernel<<<1280, 256, 0, stream>>>(wc_rm, wcp);

  // 3) fused L0: h0 = in @ Wc + bc  (replaces proj + L0 GEMM)
  P0Args pa;
  for (int r = 0; r < 4; ++r) pa.x[r] = x_reg[r];
  pa.x[4] = audio;
  projL0_kernel<<<dim3(8, 384), 256, 0, stream>>>(pa, wcp, bc, h_bf);

  // 4) GAT layers: agg0 -> gemm(W1) -> agg1 -> gemm(W2) -> agg2(MEAN)
  const size_t dynLds = 6 * 1024 * sizeof(float);
  agg_kernel<false><<<8192, 256, 0, stream>>>(h_bf, as_in[0], ad_in[0],
                                              bias_l[0], xb);
  gemm_kernel<<<dim3(8, 384), 256, 0, stream>>>(xb, wt1, h_bf, 1024, 1024);
  agg_kernel<false><<<8192, 256, 0, stream>>>(h_bf, as_in[1], ad_in[1],
                                              bias_l[1], xb);
  gemm_kernel<<<dim3(8, 384), 256, 0, stream>>>(xb, wt2, h_bf, 1024, 1024);
  agg_kernel<true><<<8192, 256, dynLds, stream>>>(h_bf, as_in[2], ad_in[2],
                                                  bias_l[2], xf);

  // 5) LayerNorm + chunk pooling -> out [16,256]
  ln_pool_kernel<<<768, 256, 0, stream>>>(xf, ln_g, ln_b, part);
  pool2_kernel<<<16, 256, 0, stream>>>(part, (float*)d_out);
}

// Round 13
// 613.997 us; speedup vs baseline: 1.1249x; 1.1249x over previous
//
#include <hip/hip_runtime.h>

// ---------------------------------------------------------------------------
// MultiModalRelationGraph — R13  (= R11 base + B-hoist gemm + batched agg loads)
// - GEMM: R7 BK=64 dbuf LDS A (global_load_lds 16B, XOR swizzle, XCD swizzle)
//   + B-fragment loads hoisted BEFORE prefetch DMAs (vmcnt retires in order:
//   hoisting lets the MFMA wait at vmcnt(4), keeping the A prefetch in flight).
// - Agg: R11 merged 6-dst blocks (4 regions + audio pair), R11 LDS/wred
//   softmax verbatim; NEW: all 10 row loads issued as raw ushort4 before any
//   cvt (hp unconditional via clamped t-1) -> one vmcnt wait, no load branch.
// - R12 lesson: proj×W0 fusion re-does the fp32 A-cvt per column block (8x
//   VALU) — reverted to separate proj (N=256) + L0 gemm.
// - Ledger: strip-mining kills agg TLP (R8/R9); per-node atomics flood (R10);
//   pure-global GEMM operands L2-BW-bound (R5); big AGPR tiles kill occ (R3).
// Node layout: region i in [i*8192,(i+1)*8192), node = i*8192 + b*512 + t.
// Audio: 32768 + b*1024 + ta.
// ---------------------------------------------------------------------------

typedef unsigned short u16;
typedef unsigned int u32;
typedef __bf16 bf16x8 __attribute__((ext_vector_type(8)));
typedef float f32x4 __attribute__((ext_vector_type(4)));

#define ASYNC16(gp, lp)                                                        \
  __builtin_amdgcn_global_load_lds(                                            \
      (const __attribute__((address_space(1))) void*)(gp),                     \
      (__attribute__((address_space(3))) void*)(lp), 16, 0, 0)

__device__ __forceinline__ u16 f2bf(float f) {
  union { float f; u32 u; } v; v.f = f;
  u32 u = v.u + 0x7FFFu + ((v.u >> 16) & 1u);  // RNE
  return (u16)(u >> 16);
}
__device__ __forceinline__ float bf2f(u16 x) {
  union { u32 u; float f; } v; v.u = ((u32)x) << 16;
  return v.f;
}
__device__ __forceinline__ float4 cvt4(ushort4 s) {
  float4 r; r.x = bf2f(s.x); r.y = bf2f(s.y); r.z = bf2f(s.z); r.w = bf2f(s.w);
  return r;
}
__device__ __forceinline__ float lrelu(float v) { return v > 0.f ? v : 0.2f * v; }
__device__ __forceinline__ float dot4(float4 a, float4 b) {
  return a.x * b.x + a.y * b.y + a.z * b.z + a.w * b.w;
}
__device__ __forceinline__ float wred(float v) {  // lane 0 valid
#pragma unroll
  for (int off = 32; off; off >>= 1) v += __shfl_down(v, off);
  return v;
}
__device__ __forceinline__ float wredx(float v) {  // all lanes valid
#pragma unroll
  for (int off = 32; off; off >>= 1) v += __shfl_xor(v, off);
  return v;
}

// ---------------- weight pack: W [K][N] fp32 -> MFMA B-fragment order -------
struct PK { const float* W[8]; u16* P[8]; int KB[8]; int NN[8]; int st[9]; };
__global__ __launch_bounds__(256) void pack_kernel(PK p) {
  const int f = blockIdx.x * 4 + (threadIdx.x >> 6);
  const int lane = threadIdx.x & 63;
  int e = 0;
  while (f >= p.st[e + 1]) ++e;
  const int local = f - p.st[e];
  const int KB = p.KB[e], N = p.NN[e];
  const int nt = local / KB, kb = local % KB;
  const float* W = p.W[e] + (size_t)(kb * 32 + (lane >> 4) * 8) * N + nt * 16 + (lane & 15);
  u16* dst = p.P[e] + ((size_t)local * 64 + lane) * 8;
  u16 o[8];
#pragma unroll
  for (int j = 0; j < 8; ++j) o[j] = f2bf(W[(size_t)j * N]);
  *(uint4*)dst = *(uint4*)o;
}

// ---------------- layer GEMM: C[M,N]=A[M,K]@W^T; BK=64 dbuf, B hoisted ------
__global__ __launch_bounds__(256) void gemm_kernel(
    const u16* __restrict__ A, const u16* __restrict__ Bp, u16* __restrict__ C,
    int K, int ldc) {
  __shared__ __align__(16) u16 As[2][2][128 * 32];
  const int KB = K >> 5;
  const int KB2 = K >> 6;
  const int w = blockIdx.y * 8 + blockIdx.x;
  const int xcd = w & 7, m = w >> 3;
  const int blockCol = (m & 7) * 128;
  const int blockRow = ((m >> 3) * 8 + xcd) * 128;
  const int tid = threadIdx.x;
  const int wave = tid >> 6, lane = tid & 63;
  const int wr = (wave >> 1) * 64, wc = (wave & 1) * 64;
  const int lr = lane & 15, lq = lane >> 4;
  const int sRow = wave * 16 + (lane >> 2);
  const int sGc = (lane & 3) ^ ((sRow >> 1) & 3);
  const size_t aOff0 = (size_t)(blockRow + sRow) * K + sGc * 8;
  const size_t aOff1 = aOff0 + (size_t)64 * K;
  const int ldsOff0 = wave * 512;
  const int ldsOff1 = 2048 + wave * 512;

  const u16* Bn[4];
#pragma unroll
  for (int ni = 0; ni < 4; ++ni)
    Bn[ni] = Bp + ((size_t)(((blockCol + wc) >> 4) + ni) * KB) * 512 + lane * 8;

  f32x4 acc[4][4] = {};

#pragma unroll
  for (int h = 0; h < 2; ++h) {
    ASYNC16(A + aOff0 + h * 32, As[0][h] + ldsOff0);
    ASYNC16(A + aOff1 + h * 32, As[0][h] + ldsOff1);
  }
  __syncthreads();

  for (int kb2 = 0; kb2 < KB2; ++kb2) {
    const int cb = kb2 & 1;
    // 1) B fragments for both halves FIRST: in-order vmcnt retirement means
    //    their wait excludes the prefetch DMAs issued below.
    bf16x8 bfr[2][4];
#pragma unroll
    for (int h = 0; h < 2; ++h)
#pragma unroll
      for (int ni = 0; ni < 4; ++ni)
        bfr[h][ni] = *(const bf16x8*)(Bn[ni] + (size_t)(kb2 * 2 + h) * 512);
    // 2) prefetch next 64-wide A block into alternate buffer
    if (kb2 + 1 < KB2) {
      const size_t k1 = (size_t)(kb2 + 1) * 64;
#pragma unroll
      for (int h = 0; h < 2; ++h) {
        ASYNC16(A + aOff0 + k1 + h * 32, As[cb ^ 1][h] + ldsOff0);
        ASYNC16(A + aOff1 + k1 + h * 32, As[cb ^ 1][h] + ldsOff1);
      }
    }
    // 3) compute
#pragma unroll
    for (int h = 0; h < 2; ++h) {
      const u16* cur = As[cb][h];
      bf16x8 af[4];
#pragma unroll
      for (int mi = 0; mi < 4; ++mi) {
        const int R = wr + mi * 16 + lr;
        const int cp = lq ^ ((R >> 1) & 3);
        af[mi] = *(const bf16x8*)(cur + R * 32 + cp * 8);
      }
#pragma unroll
      for (int mi = 0; mi < 4; ++mi)
#pragma unroll
        for (int ni = 0; ni < 4; ++ni)
          acc[mi][ni] = __builtin_amdgcn_mfma_f32_16x16x32_bf16(af[mi], bfr[h][ni],
                                                                acc[mi][ni], 0, 0, 0);
    }
    __syncthreads();
  }
#pragma unroll
  for (int mi = 0; mi < 4; ++mi)
#pragma unroll
    for (int ni = 0; ni < 4; ++ni) {
      const int col = blockCol + wc + ni * 16 + lr;
#pragma unroll
      for (int r = 0; r < 4; ++r) {
        const int row = blockRow + wr + mi * 16 + lq * 4 + r;
        C[(size_t)row * ldc + col] = f2bf(acc[mi][ni][r]);
      }
    }
}

// ---------------- fused input projection (fp32 A in-register cvt) -----------
struct ProjArgs { const float* x[5]; const u16* w[5]; const float* b[5]; };
__global__ __launch_bounds__(256) void proj_kernel(ProjArgs pa,
                                                   u16* __restrict__ C) {
  __shared__ __align__(16) u16 As[128 * 32];
  const int blockRow = blockIdx.y * 128, blockCol = blockIdx.x * 128;
  const int reg = blockRow >= 32768 ? 4 : (blockRow >> 13);
  const int regBase = reg == 4 ? 32768 : reg * 8192;
  const float* Af = pa.x[reg] + (size_t)(blockRow - regBase) * 512;
  const u16* Bp = pa.w[reg];
  const int tid = threadIdx.x;
  const int wave = tid >> 6, lane = tid & 63;
  const int wr = (wave >> 1) * 64, wc = (wave & 1) * 64;
  const int lr = lane & 15, lq = lane >> 4;
  const int rr = tid >> 2;
  const int cphys = tid & 3;
  const int sGc = cphys ^ ((tid >> 3) & 3);

  const u16* Bn[4];
#pragma unroll
  for (int ni = 0; ni < 4; ++ni)
    Bn[ni] = Bp + ((size_t)(((blockCol + wc) >> 4) + ni) * 16) * 512 + lane * 8;

  f32x4 acc[4][4] = {};

  for (int k0 = 0; k0 < 512; k0 += 32) {
    __syncthreads();
    bf16x8 bfr[4];
#pragma unroll
    for (int ni = 0; ni < 4; ++ni)
      bfr[ni] = *(const bf16x8*)(Bn[ni] + (size_t)k0 * 16);
#pragma unroll
    for (int i = 0; i < 2; ++i) {
      const int row = i * 64 + rr;
      const float* ap = Af + (size_t)row * 512 + k0 + sGc * 8;
      float4 f0 = *(const float4*)(ap);
      float4 f1 = *(const float4*)(ap + 4);
      uint4 pk;
      pk.x = (u32)f2bf(f0.x) | ((u32)f2bf(f0.y) << 16);
      pk.y = (u32)f2bf(f0.z) | ((u32)f2bf(f0.w) << 16);
      pk.z = (u32)f2bf(f1.x) | ((u32)f2bf(f1.y) << 16);
      pk.w = (u32)f2bf(f1.z) | ((u32)f2bf(f1.w) << 16);
      *(uint4*)(&As[row * 32 + cphys * 8]) = pk;
    }
    __syncthreads();
    bf16x8 af[4];
#pragma unroll
    for (int mi = 0; mi < 4; ++mi) {
      const int R = wr + mi * 16 + lr;
      const int cp = lq ^ ((R >> 1) & 3);
      af[mi] = *(const bf16x8*)(&As[R * 32 + cp * 8]);
    }
#pragma unroll
    for (int mi = 0; mi < 4; ++mi)
#pragma unroll
      for (int ni = 0; ni < 4; ++ni)
        acc[mi][ni] = __builtin_amdgcn_mfma_f32_16x16x32_bf16(af[mi], bfr[ni],
                                                              acc[mi][ni], 0, 0, 0);
  }
  const float* bias = pa.b[reg];
#pragma unroll
  for (int mi = 0; mi < 4; ++mi)
#pragma unroll
    for (int ni = 0; ni < 4; ++ni) {
      const int col = blockCol + wc + ni * 16 + lr;
      const float bv = bias[col];
#pragma unroll
      for (int r = 0; r < 4; ++r) {
        const int row = blockRow + wr + mi * 16 + lq * 4 + r;
        C[(size_t)row * 256 + col] = f2bf(acc[mi][ni][r] + bv);
      }
    }
}

// ---------------- merged aggregation: block (b,t) -> 6 dst nodes ------------
// All 10 row loads issued raw first (hp unconditional, clamped t-1), cvt after
// -> single vmcnt wait. Softmax: R11 LDS/wred scheme verbatim.
template <bool MEAN>
__global__ __launch_bounds__(256) void agg_kernel(
    const u16* __restrict__ h, const float* __restrict__ a_s,
    const float* __restrict__ a_d, const float* __restrict__ bias,
    void* __restrict__ out) {
  extern __shared__ float red[];  // MEAN only: [6][1024]
  const int tid = threadIdx.x;
  const int head = tid >> 6, lane = tid & 63;
  const int c4 = tid * 4;
  const float4 sa = *(const float4*)(a_s + c4);
  const float4 da = *(const float4*)(a_d + c4);
  __shared__ float asL[4][4], adL[4][4], apL[4][4], aeS[4], aeD[4];
  __shared__ float alpha[4][4][5], alphaA[4][3];

  const int bt = blockIdx.x;
  const int b = bt >> 9, t = bt & 511;
  const bool hasPrev = t > 0;
  const int btp = hasPrev ? bt - 1 : bt;  // clamped: loads valid, result unused at t==0
  const int nodeE = 32768 + b * 1024 + 2 * t;
  const int nodeO = nodeE + 1;

  // ---- batched raw loads (no cvt until all issued) ----
  ushort4 rv[4], rp[4], raeR, raoR;
#pragma unroll
  for (int r = 0; r < 4; ++r)
    rv[r] = *(const ushort4*)(h + (size_t)(r * 8192 + bt) * 1024 + c4);
  raeR = *(const ushort4*)(h + (size_t)nodeE * 1024 + c4);
  raoR = *(const ushort4*)(h + (size_t)nodeO * 1024 + c4);
#pragma unroll
  for (int r = 0; r < 4; ++r)
    rp[r] = *(const ushort4*)(h + (size_t)(r * 8192 + btp) * 1024 + c4);

  float4 hv[4], hp[4];
#pragma unroll
  for (int r = 0; r < 4; ++r) hv[r] = cvt4(rv[r]);
  float4 hae = cvt4(raeR), hao = cvt4(raoR);
#pragma unroll
  for (int r = 0; r < 4; ++r) hp[r] = cvt4(rp[r]);

  // dots (wave w == head w); lane0-valid wred, stash to LDS
#pragma unroll
  for (int r = 0; r < 4; ++r) {
    float ss = wred(dot4(hv[r], sa));
    float dd = wred(dot4(hv[r], da));
    float sp = hasPrev ? wred(dot4(hp[r], sa)) : 0.f;
    if (lane == 0) { asL[r][head] = ss; adL[r][head] = dd; apL[r][head] = sp; }
  }
  {
    float se = wred(dot4(hae, sa));
    float de = wred(dot4(hae, da));
    if (lane == 0) { aeS[head] = se; aeD[head] = de; }
  }
  __syncthreads();
  if (tid < 16) {
    const int j = tid >> 2, hh = tid & 3;
    const float ad = adL[j][hh];
    float e[5];
#pragma unroll
    for (int r = 0; r < 4; ++r) e[r] = lrelu(asL[r][hh] + ad);
    int cnt = 4;
    if (hasPrev) { e[4] = lrelu(apL[j][hh] + ad); cnt = 5; }
    float mx = e[0];
    for (int k = 1; k < cnt; ++k) mx = fmaxf(mx, e[k]);
    float s = 0.f, ex[5];
    for (int k = 0; k < cnt; ++k) { ex[k] = __expf(e[k] - mx); s += ex[k]; }
    const float inv = 1.f / (s + 1e-16f);
#pragma unroll
    for (int k = 0; k < 5; ++k) alpha[j][hh][k] = (k < cnt) ? ex[k] * inv : 0.f;
  } else if (tid < 20) {
    const int hh = tid - 16;  // audio-even softmax: {self, left eye, right eye}
    const float ad = aeD[hh];
    const float e0 = lrelu(aeS[hh] + ad);
    const float e1 = lrelu(asL[1][hh] + ad);
    const float e2 = lrelu(asL[2][hh] + ad);
    const float mx = fmaxf(e0, fmaxf(e1, e2));
    const float x0 = __expf(e0 - mx), x1 = __expf(e1 - mx), x2 = __expf(e2 - mx);
    const float inv = 1.f / (x0 + x1 + x2 + 1e-16f);
    alphaA[hh][0] = x0 * inv; alphaA[hh][1] = x1 * inv; alphaA[hh][2] = x2 * inv;
  }
  __syncthreads();

  float4 av[6];
#pragma unroll
  for (int j = 0; j < 4; ++j) {
    const float* al = &alpha[j][head][0];
    float4 acc;
    acc.x = al[0] * hv[0].x + al[1] * hv[1].x + al[2] * hv[2].x + al[3] * hv[3].x;
    acc.y = al[0] * hv[0].y + al[1] * hv[1].y + al[2] * hv[2].y + al[3] * hv[3].y;
    acc.z = al[0] * hv[0].z + al[1] * hv[1].z + al[2] * hv[2].z + al[3] * hv[3].z;
    acc.w = al[0] * hv[0].w + al[1] * hv[1].w + al[2] * hv[2].w + al[3] * hv[3].w;
    if (hasPrev) {
      const float a4 = al[4];
      acc.x += a4 * hp[j].x; acc.y += a4 * hp[j].y;
      acc.z += a4 * hp[j].z; acc.w += a4 * hp[j].w;
    }
    av[j] = acc;
  }
  {
    const float a0 = alphaA[head][0], a1 = alphaA[head][1], a2 = alphaA[head][2];
    float4 acc;
    acc.x = a0 * hae.x + a1 * hv[1].x + a2 * hv[2].x;
    acc.y = a0 * hae.y + a1 * hv[1].y + a2 * hv[2].y;
    acc.z = a0 * hae.z + a1 * hv[1].z + a2 * hv[2].z;
    acc.w = a0 * hae.w + a1 * hv[1].w + a2 * hv[2].w;
    av[4] = acc;
    av[5] = hao;  // odd audio: self-loop only
  }

  if constexpr (!MEAN) {
    const float4 bv = *(const float4*)(bias + c4);
    u16* ob = (u16*)out;
    size_t rows[6];
#pragma unroll
    for (int j = 0; j < 4; ++j) rows[j] = (size_t)(j * 8192 + bt);
    rows[4] = (size_t)nodeE; rows[5] = (size_t)nodeO;
#pragma unroll
    for (int k = 0; k < 6; ++k) {
      ushort4 o;
      o.x = f2bf(av[k].x + bv.x); o.y = f2bf(av[k].y + bv.y);
      o.z = f2bf(av[k].z + bv.z); o.w = f2bf(av[k].w + bv.w);
      *(ushort4*)(ob + rows[k] * 1024 + c4) = o;
    }
  } else {
#pragma unroll
    for (int k = 0; k < 6; ++k) *(float4*)(&red[k * 1024 + c4]) = av[k];
    __syncthreads();
    const float bb = bias[tid];
    float* of = (float*)out;
    size_t rows[6];
#pragma unroll
    for (int j = 0; j < 4; ++j) rows[j] = (size_t)(j * 8192 + bt);
    rows[4] = (size_t)nodeE; rows[5] = (size_t)nodeO;
#pragma unroll
    for (int k = 0; k < 6; ++k) {
      const float v = 0.25f * (red[k * 1024 + tid] + red[k * 1024 + tid + 256] +
                               red[k * 1024 + tid + 512] + red[k * 1024 + tid + 768]) + bb;
      of[rows[k] * 256 + tid] = v;
    }
  }
}

// ---------------- barrier-free LayerNorm(256) + partial pooling -------------
__global__ __launch_bounds__(256) void ln_pool_kernel(
    const float* __restrict__ xf, const float* __restrict__ g,
    const float* __restrict__ bb, float* __restrict__ part) {
  const int tid = threadIdx.x;
  const int wave = tid >> 6, lane = tid & 63;
  const int node0 = blockIdx.x * 64 + wave * 16;
  const float4 g4 = *(const float4*)(g + lane * 4);
  const float4 b4 = *(const float4*)(bb + lane * 4);
  float4 acc = {0.f, 0.f, 0.f, 0.f};
  for (int i = 0; i < 16; ++i) {
    const float4 v = *(const float4*)(xf + (size_t)(node0 + i) * 256 + lane * 4);
    const float s = wredx(v.x + v.y + v.z + v.w);
    const float q = wredx(v.x * v.x + v.y * v.y + v.z * v.z + v.w * v.w);
    const float mean = s * (1.f / 256.f);
    const float var = q * (1.f / 256.f) - mean * mean;
    const float rstd = rsqrtf(var + 1e-5f);
    acc.x += (v.x - mean) * rstd * g4.x + b4.x;
    acc.y += (v.y - mean) * rstd * g4.y + b4.y;
    acc.z += (v.z - mean) * rstd * g4.z + b4.z;
    acc.w += (v.w - mean) * rstd * g4.w + b4.w;
  }
  *(float4*)(part + (size_t)(blockIdx.x * 4 + wave) * 256 + lane * 4) = acc;
}

__global__ __launch_bounds__(256) void pool2_kernel(const float* __restrict__ part,
                                                    float* __restrict__ out) {
  const int chunk = blockIdx.x;
  const int c = threadIdx.x;
  float s = 0.f;
  for (int i = 0; i < 192; ++i) s += part[(size_t)(chunk * 192 + i) * 256 + c];
  out[chunk * 256 + c] = s * (1.f / 3072.f);
}

// ---------------------------------------------------------------------------
extern "C" void kernel_launch(void* const* d_in, const int* in_sizes, int n_in,
                              void* d_out, int out_size, void* d_ws, size_t ws_size,
                              hipStream_t stream) {
  const float* x_reg[4] = {(const float*)d_in[0], (const float*)d_in[1],
                           (const float*)d_in[2], (const float*)d_in[3]};
  const float* audio = (const float*)d_in[4];
  const float* w_reg[4] = {(const float*)d_in[5], (const float*)d_in[7],
                           (const float*)d_in[9], (const float*)d_in[11]};
  const float* b_reg[4] = {(const float*)d_in[6], (const float*)d_in[8],
                           (const float*)d_in[10], (const float*)d_in[12]};
  const float* w_aud = (const float*)d_in[13];
  const float* b_aud = (const float*)d_in[14];
  const float* Wl[3] = {(const float*)d_in[15], (const float*)d_in[19],
                        (const float*)d_in[23]};
  const float* as_in[3] = {(const float*)d_in[16], (const float*)d_in[20],
                           (const float*)d_in[24]};
  const float* ad_in[3] = {(const float*)d_in[17], (const float*)d_in[21],
                           (const float*)d_in[25]};
  const float* bias_l[3] = {(const float*)d_in[18], (const float*)d_in[22],
                            (const float*)d_in[26]};
  const float* ln_g = (const float*)d_in[27];
  const float* ln_b = (const float*)d_in[28];

  // workspace layout (<200 MiB)
  char* ws = (char*)d_ws;
  u16* h_bf = (u16*)ws;                    // [N,1024] bf16 (96 MiB)
  float* part = (float*)ws;                // ln partials (h dead by then)
  u16* xb = (u16*)(ws + 100663296);        // [N,1024] bf16 x buffer
  float* xf = (float*)xb;                  // layer-2 output [N,256] fp32
  u16* wt = (u16*)(ws + 201326592);        // packed bf16 weights (~5.8 MiB)

  u16* wtp[5];
  for (int r = 0; r < 5; ++r) wtp[r] = wt + (size_t)r * 131072;
  u16* wt0 = wt + 655360;   // 512 frags
  u16* wt1 = wt + 917504;   // 2048 frags
  u16* wt2 = wt + 1966080;  // 2048 frags

  // 1) pack all weights into MFMA fragment order
  PK pk;
  for (int r = 0; r < 4; ++r) { pk.W[r] = w_reg[r]; pk.P[r] = wtp[r]; pk.KB[r] = 16; pk.NN[r] = 256; }
  pk.W[4] = w_aud; pk.P[4] = wtp[4]; pk.KB[4] = 16; pk.NN[4] = 256;
  pk.W[5] = Wl[0]; pk.P[5] = wt0; pk.KB[5] = 8;  pk.NN[5] = 1024;
  pk.W[6] = Wl[1]; pk.P[6] = wt1; pk.KB[6] = 32; pk.NN[6] = 1024;
  pk.W[7] = Wl[2]; pk.P[7] = wt2; pk.KB[7] = 32; pk.NN[7] = 1024;
  pk.st[0] = 0;
  {
    const int nfr[8] = {256, 256, 256, 256, 256, 512, 2048, 2048};
    int acc = 0;
    for (int e = 0; e < 8; ++e) { acc += nfr[e]; pk.st[e + 1] = acc; }
  }
  pack_kernel<<<pk.st[8] / 4, 256, 0, stream>>>(pk);

  // 2) fused input projections (fp32 in, bf16 out) -> x0 [N,256]
  ProjArgs pa;
  for (int r = 0; r < 4; ++r) { pa.x[r] = x_reg[r]; pa.w[r] = wtp[r]; pa.b[r] = b_reg[r]; }
  pa.x[4] = audio; pa.w[4] = wtp[4]; pa.b[4] = b_aud;
  proj_kernel<<<dim3(2, 384), 256, 0, stream>>>(pa, xb);

  // 3) three GAT layers: BK=64 dbuf gemm (B hoisted) -> merged agg
  const u16* wl[3] = {wt0, wt1, wt2};
  const int Kl[3] = {256, 1024, 1024};
  const size_t dynLds = 6 * 1024 * sizeof(float);
  for (int l = 0; l < 3; ++l) {
    gemm_kernel<<<dim3(8, 384), 256, 0, stream>>>(xb, wl[l], h_bf, Kl[l], 1024);
    if (l < 2)
      agg_kernel<false><<<8192, 256, 0, stream>>>(h_bf, as_in[l], ad_in[l],
                                                  bias_l[l], xb);
    else
      agg_kernel<true><<<8192, 256, dynLds, stream>>>(h_bf, as_in[l], ad_in[l],
                                                      bias_l[l], xf);
  }

  // 4) LayerNorm + chunk pooling -> out [16,256]
  ln_pool_kernel<<<768, 256, 0, stream>>>(xf, ln_g, ln_b, part);
  pool2_kernel<<<16, 256, 0, stream>>>(part, (float*)d_out);
}